// Round 6
// baseline (801.723 us; speedup 1.0000x reference)
//
#include <hip/hip_runtime.h>
#include <math.h>

// Problem constants
#define B_ 16
#define C_ 64
#define H_ 128
#define W_ 128
#define HW_ (H_*W_)
#define OUT_ELEMS 16777216   // B*C*H*W

// Workspace byte offsets
#define CHM_B    0                      // 512 f32
#define PWA_B    2048                   // 16384 u16
#define AH_B     34816                  // 258048 u16
#define FEA_B(s) (550912u + (size_t)(s)*33554432u)  // 4 x 16777216 u16

// A-image u16 offsets within AH
#define A_S0   0
#define A_S(s) (36864 + ((s)-1)*73728)  // s = 1..3

typedef __attribute__((ext_vector_type(4))) short  v4s;
typedef __attribute__((ext_vector_type(8))) short  v8s;
typedef __attribute__((ext_vector_type(4))) float  v4f;

__device__ __forceinline__ ushort f2bf(float f) {
    unsigned u = __builtin_bit_cast(unsigned, f);
    unsigned r = u + 0x7FFFu + ((u >> 16) & 1u);
    return (ushort)(r >> 16);
}

// ---------------------------------------------------------------------------
__global__ __launch_bounds__(64) void mask_kernel(
    const float* __restrict__ gum, const float* __restrict__ par,
    float* __restrict__ chm, float* __restrict__ out_tail)
{
    int c = threadIdx.x;
    #pragma unroll
    for (int i = 0; i < 4; ++i) {
        int base = (c*4 + i)*2;
        float g0 = -logf(-logf(gum[base]));
        float g1 = -logf(-logf(gum[base+1]));
        float a0 = par[base] + g0, a1 = par[base+1] + g1;
        float mx = fmaxf(a0, a1);
        float e0 = expf(a0 - mx), e1 = expf(a1 - mx);
        float inv = 1.0f / (e0 + e1);
        float m0 = e0*inv, m1 = e1*inv;
        chm[base] = m0; chm[base+1] = m1;
        out_tail[base] = m0; out_tail[base+1] = m1;
    }
}

// ---------------------------------------------------------------------------
// Build bf16 A-images (gate-folded weights) + bf16 pw weights.
__global__ __launch_bounds__(256) void prep_kernel(
    const float* __restrict__ w0, const float* __restrict__ w1,
    const float* __restrict__ w2, const float* __restrict__ w3,
    const float* __restrict__ wc, const float* __restrict__ chm,
    ushort* __restrict__ AH, ushort* __restrict__ pwA)
{
    int idx = blockIdx.x*256 + threadIdx.x;   // < 274432
    if (idx < 36864) {
        int blk = idx >> 11;            // c*9+t, 0..17
        int r3  = idx & 2047;
        int oc = r3 >> 5, icl = r3 & 31;
        int cc = blk / 9, t = blk - 9*cc;
        int ic = cc*32 + icl;
        AH[idx] = f2bf(w0[(oc*64 + ic)*9 + t]);
    } else if (idx < 258048) {
        int j = idx - 36864;
        int s = 1 + j / 73728;
        int r = j % 73728;
        int blk = r >> 12;              // 0..17
        int r3  = r & 4095;
        int ocM = r3 >> 5, icl = r3 & 31;
        int cc = blk / 9, t = blk - 9*cc;
        int ic = cc*32 + icl;
        int oc = ocM >> 1, set = ocM & 1;
        const float* wsrc = (s == 1) ? w1 : (s == 2 ? w2 : w3);
        AH[idx] = f2bf(wsrc[(oc*64 + ic)*9 + t] * chm[(ic*4 + s)*2 + set]);
    } else {
        int r = idx - 258048;           // < 16384
        pwA[r] = f2bf(wc[r]);
    }
}

// ---------------------------------------------------------------------------
// MFMA conv, pure bf16. Block = one (b,h) row, 128 px. M = 64*NSETS rows.
// 512 threads / 8 waves, MT=1 everywhere (round-6 spill fix: round 5's
// MT=2 + ring-4 bill (~92 regs) blew the 64 VGPR + 64 AGPR split at 4
// waves/SIMD and spilled to scratch, +159MB HBM traffic).
//   NSETS=2: 8M x 1N  — wave = 16 ocM rows x 128 px. acc 32(AGPR) + af 16
//            + stg 12 + temps ~= 55 VGPR. A-rows read by exactly ONE wave
//            (A L2-traffic halved vs round 4); B-tile reads duplicate 8x
//            (~30us LDS pipe across dispatch — under the wall).
//   NSETS=1: 4M x 2N  — wave = 16 rows x 64 px. acc 16 + af 16 + stgF 24.
// LDS layout: sB[colIdx*36 + (ic ^ (((colIdx>>3)&7)<<2))] — 3-bit XOR swizzle
// (4-way write conflict). Reads: two aligned b64 loads, reassembled in order.
// Halo zero-init: ONLY columns {ry*130+0, ry*130+129}, disjoint from scatter.
// A frags: ring-4 (3-tap-ahead) prefetch, compile-time ring indices.
// Schedule: verified 3-barrier structure (rounds 4/5 both passed with it).
template<int NSETS, bool INF32>
__global__ __launch_bounds__(512, 4) void conv_bf16(
    const void* __restrict__ inv, const ushort* __restrict__ A,
    const float* __restrict__ chm, const float* __restrict__ spa,
    ushort* __restrict__ feaOut, int stage)
{
    constexpr int MOC = 64*NSETS;
    constexpr int WN  = (NSETS == 2) ? 1 : 2;   // waves along N
    constexpr int NT  = (NSETS == 2) ? 8 : 4;   // 16px n-tiles per wave
    __shared__ __align__(16) ushort sB[3*130*36]; // 28080 B

    const int tid  = threadIdx.x;
    const int lane = tid & 63, wave = tid >> 6;   // 0..7
    const int wrow = (WN == 1) ? wave : (wave >> 1);
    const int wcol = (WN == 1) ? 0    : (wave & 1);
    const int q = lane >> 4, ln16 = lane & 15;
    // XCD-aware remap (grid 2048 = 8*256): contiguous (b,h) chunk per XCD.
    const int wk = (blockIdx.x & 7)*256 + (blockIdx.x >> 3);
    const int h = wk & 127, b = wk >> 7;

    v4f acc[NT];
    #pragma unroll
    for (int n = 0; n < NT; ++n) acc[n] = (v4f){0.f, 0.f, 0.f, 0.f};

    const int aRow = (wrow*16 + ln16)*32 + q*8;

    // staging registers (reused across chunks) + A-frag ring (MT=1)
    v8s stg[3];
    v4f stgF[6];
    v8s af[4];

    auto issue = [&](int ic0) {
        #pragma unroll
        for (int it = 0; it < 3; ++it) {
            int i  = it*512 + tid;     // [0,1536)
            int ry = i >> 9;           // 0..2
            int r  = i & 511;
            int ic = r >> 4, wv = r & 15;
            int gh = h - 1 + ry;
            if constexpr (INF32) {
                v4f a0 = (v4f){0.f,0.f,0.f,0.f}, a1 = a0;
                if ((unsigned)gh < 128u) {
                    const float* s = (const float*)inv +
                        ((size_t)((b*C_ + ic0 + ic)*H_ + gh)*W_ + wv*8);
                    a0 = *(const v4f*)(const void*)s;
                    a1 = *(const v4f*)(const void*)(s + 4);
                }
                stgF[it*2] = a0; stgF[it*2+1] = a1;
            } else {
                v8s v = (v8s){0,0,0,0,0,0,0,0};
                if ((unsigned)gh < 128u)
                    v = *(const v8s*)(const void*)((const ushort*)inv +
                        ((size_t)((b*C_ + ic0 + ic)*H_ + gh)*W_ + wv*8));
                stg[it] = v;
            }
        }
    };
    auto scatter = [&]() {
        #pragma unroll
        for (int it = 0; it < 3; ++it) {
            int i  = it*512 + tid;
            int ry = i >> 9;
            int r  = i & 511;
            int ic = r >> 4, wv = r & 15;
            int colBase = ry*130 + wv*8 + 1;
            ushort vals[8];
            if constexpr (INF32) {
                #pragma unroll
                for (int j = 0; j < 4; ++j) {
                    vals[j]   = f2bf(stgF[it*2][j]);
                    vals[4+j] = f2bf(stgF[it*2+1][j]);
                }
            } else {
                #pragma unroll
                for (int j = 0; j < 8; ++j) vals[j] = (ushort)stg[it][j];
            }
            #pragma unroll
            for (int j = 0; j < 8; ++j) {
                int colIdx = colBase + j;
                int s3 = (colIdx >> 3) & 7;
                sB[colIdx*36 + (ic ^ (s3 << 2))] = vals[j];
            }
        }
    };
    auto prolog = [&](const ushort* Ab) {
        #pragma unroll
        for (int tp = 0; tp < 3; ++tp)
            af[tp] = *(const v8s*)(const void*)(Ab + tp*MOC*32 + aRow);
    };
    auto compute = [&](const ushort* Ab) {
        #pragma unroll
        for (int t = 0; t < 9; ++t) {
            if (t < 6)
                af[(t+3)&3] = *(const v8s*)(const void*)(Ab + (t+3)*MOC*32 + aRow);
            const int ky = t/3, kx = t - 3*(t/3);
            #pragma unroll
            for (int nt = 0; nt < NT; ++nt) {
                int colIdx = ky*130 + wcol*64 + nt*16 + ln16 + kx;
                int s3 = (colIdx >> 3) & 7;
                int base = colIdx*36 + ((q ^ (s3 >> 1)) << 3);
                int lo = base + ((s3 & 1) << 2);
                int hi = base + (((s3 & 1) ^ 1) << 2);
                v4s va = *(const v4s*)(const void*)(sB + lo);   // ic jj 0..3
                v4s vb = *(const v4s*)(const void*)(sB + hi);   // ic jj 4..7
                v8s bf = __builtin_shufflevector(va, vb, 0, 1, 2, 3, 4, 5, 6, 7);
                acc[nt] = __builtin_amdgcn_mfma_f32_16x16x32_bf16(af[t&3], bf, acc[nt], 0, 0, 0);
            }
        }
    };

    // -------- schedule (verified 3-barrier structure) --------
    issue(0);                 // chunk-0 fea loads in flight
    prolog(A);                // chunk-0 A taps 0-2 in flight
    // zero ONLY halo columns colIdx = ry*130 + {0,129} (216 u16 total).
    if (tid < 216) {
        int colSel = tid / 36;          // 0..5
        int icz    = tid - colSel*36;   // 0..35
        int ry     = colSel >> 1;
        int colIdx = ry*130 + ((colSel & 1) ? 129 : 0);
        sB[colIdx*36 + icz] = 0;
    }
    scatter();                // waits chunk-0 fea; disjoint from halo zeroes
    issue(32);                // chunk-1 fea flies under barrier+compute
    __syncthreads();          // tile 0 ready
    compute(A);
    prolog(A + 9*MOC*32);     // chunk-1 A taps 0-2 in flight
    __syncthreads();          // tile-0 reads done
    scatter();                // chunk-1 (regs already landed)
    __syncthreads();          // tile 1 ready
    compute(A + 9*MOC*32);

    // epilogue: gates + relu, bf16 store
    const float* spaRow = &spa[b*HW_ + h*W_];
    #pragma unroll
    for (int nt = 0; nt < NT; ++nt) {
        int px = wcol*64 + nt*16 + ln16;
        float sp = spaRow[px];
        if constexpr (NSETS == 2) {
            #pragma unroll
            for (int rp = 0; rp < 2; ++rp) {
                int oc = wrow*8 + q*2 + rp;
                float md = chm[(oc*4 + stage)*2 + 0];
                float ms = chm[(oc*4 + stage)*2 + 1];
                float f = acc[nt][2*rp]*(ms*sp + md)
                        + acc[nt][2*rp+1]*((ms + md)*sp);
                feaOut[((size_t)(b*C_ + oc)*H_ + h)*W_ + px] = f2bf(fmaxf(f, 0.f));
            }
        } else {
            #pragma unroll
            for (int r = 0; r < 4; ++r) {
                int oc = wrow*16 + q*4 + r;
                float md = chm[(oc*4 + stage)*2 + 0];
                float ms = chm[(oc*4 + stage)*2 + 1];
                float f = acc[nt][r]*(ms*sp + md);
                feaOut[((size_t)(b*C_ + oc)*H_ + h)*W_ + px] = f2bf(fmaxf(f, 0.f));
            }
        }
    }
}

// ---------------------------------------------------------------------------
// Final pointwise: out[b,o,px] = sum_{k=0..255} wc[o][k]*fea_{k/64}[k%64][px] + bc[o]
// Block = 64 px of one (b,h) row. MFMA: M=64, N=64, K=256.
// launch_bounds(256,4): ~80-reg bill fits 128 -> 4 waves/SIMD; XCD swizzle.
__global__ __launch_bounds__(256, 4) void pw_final(
    const ushort* __restrict__ fea, const ushort* __restrict__ pwA,
    const float* __restrict__ bc, float* __restrict__ out)
{
    __shared__ __align__(16) ushort sF[64*260];   // 33280 B

    const int tid  = threadIdx.x;
    const int lane = tid & 63, wave = tid >> 6;
    const int wrow = wave >> 1, wcol = wave & 1;
    const int q = lane >> 4, ln16 = lane & 15;
    const int wk = (blockIdx.x & 7)*512 + (blockIdx.x >> 3);   // grid = 4096
    const int half = wk & 1;
    const int h = (wk >> 1) & 127;
    const int b = wk >> 8;
    const int px0 = half*64;

    {
        v8s stg[8];
        #pragma unroll
        for (int it = 0; it < 8; ++it) {
            int i  = it*256 + tid;   // [0,2048)
            int s  = i >> 9;
            int r  = i & 511;
            int ic = r >> 3, pxv = r & 7;
            stg[it] = *(const v8s*)(const void*)(
                fea + (size_t)s*OUT_ELEMS + ((size_t)(b*C_ + ic)*H_ + h)*W_ + px0 + pxv*8);
        }
        #pragma unroll
        for (int it = 0; it < 8; ++it) {
            int i  = it*256 + tid;
            int s  = i >> 9;
            int r  = i & 511;
            int ic = r >> 3, pxv = r & 7;
            int kS = (s*64 + ic) ^ ((pxv & 3) << 3);
            ushort* dst = &sF[(pxv*8)*260 + kS];
            #pragma unroll
            for (int j = 0; j < 8; ++j) dst[j*260] = (ushort)stg[it][j];
        }
    }
    __syncthreads();

    v4f acc[2][2];
    #pragma unroll
    for (int m = 0; m < 2; ++m)
        #pragma unroll
        for (int n = 0; n < 2; ++n) acc[m][n] = (v4f){0.f, 0.f, 0.f, 0.f};

    #pragma unroll
    for (int ks = 0; ks < 8; ++ks) {
        v8s a[2];
        #pragma unroll
        for (int m = 0; m < 2; ++m)
            a[m] = *(const v8s*)(const void*)(pwA + (wrow*32 + m*16 + ln16)*256 + ks*32 + q*8);
        #pragma unroll
        for (int n = 0; n < 2; ++n) {
            int px = wcol*32 + n*16 + ln16;
            int swz = (px >> 3) & 3;
            v4s va = *(const v4s*)(const void*)(sF + px*260 + ks*32 + ((q ^ swz) << 3));
            v4s vb = *(const v4s*)(const void*)(sF + px*260 + ks*32 + ((q ^ swz) << 3) + 4);
            v8s bf = __builtin_shufflevector(va, vb, 0, 1, 2, 3, 4, 5, 6, 7);
            #pragma unroll
            for (int m = 0; m < 2; ++m)
                acc[m][n] = __builtin_amdgcn_mfma_f32_16x16x32_bf16(a[m], bf, acc[m][n], 0, 0, 0);
        }
    }

    #pragma unroll
    for (int n = 0; n < 2; ++n) {
        int px = px0 + wcol*32 + n*16 + ln16;
        #pragma unroll
        for (int m = 0; m < 2; ++m)
            #pragma unroll
            for (int r = 0; r < 4; ++r) {
                int o = wrow*32 + m*16 + q*4 + r;
                out[((size_t)(b*C_ + o)*H_ + h)*W_ + px] = acc[m][n][r] + bc[o];
            }
    }
}

// ---------------------------------------------------------------------------
extern "C" void kernel_launch(void* const* d_in, const int* in_sizes, int n_in,
                              void* d_out, int out_size, void* d_ws, size_t ws_size,
                              hipStream_t stream)
{
    const float* x0  = (const float*)d_in[0];
    const float* spa = (const float*)d_in[1];
    const float* gum = (const float*)d_in[2];
    const float* par = (const float*)d_in[3];
    const float* w0  = (const float*)d_in[4];
    const float* w1  = (const float*)d_in[5];
    const float* w2  = (const float*)d_in[6];
    const float* w3  = (const float*)d_in[7];
    const float* wc  = (const float*)d_in[8];
    const float* bc  = (const float*)d_in[9];
    float* out = (float*)d_out;
    char*  ws  = (char*)d_ws;

    float*  chm = (float*)(ws + CHM_B);
    ushort* pwA = (ushort*)(ws + PWA_B);
    ushort* AH  = (ushort*)(ws + AH_B);
    ushort* fea0 = (ushort*)(ws + FEA_B(0));
    ushort* fea1 = (ushort*)(ws + FEA_B(1));
    ushort* fea2 = (ushort*)(ws + FEA_B(2));
    ushort* fea3 = (ushort*)(ws + FEA_B(3));

    mask_kernel<<<1, 64, 0, stream>>>(gum, par, chm, out + OUT_ELEMS);
    prep_kernel<<<1072, 256, 0, stream>>>(w0, w1, w2, w3, wc, chm, AH, pwA);

    conv_bf16<1, true ><<<2048, 512, 0, stream>>>(x0,   AH + A_S0,  chm, spa, fea0, 0);
    conv_bf16<2, false><<<2048, 512, 0, stream>>>(fea0, AH + A_S(1), chm, spa, fea1, 1);
    conv_bf16<2, false><<<2048, 512, 0, stream>>>(fea1, AH + A_S(2), chm, spa, fea2, 2);
    conv_bf16<2, false><<<2048, 512, 0, stream>>>(fea2, AH + A_S(3), chm, spa, fea3, 3);

    pw_final<<<4096, 256, 0, stream>>>(fea0, pwA, bc, out);
}

// Round 7
// 388.514 us; speedup vs baseline: 2.0636x; 2.0636x over previous
//
#include <hip/hip_runtime.h>
#include <math.h>

// Problem constants
#define B_ 16
#define C_ 64
#define H_ 128
#define W_ 128
#define HW_ (H_*W_)
#define OUT_ELEMS 16777216   // B*C*H*W

// Workspace byte offsets
#define CHM_B    0                      // 512 f32
#define PWA_B    2048                   // 16384 u16
#define AH_B     34816                  // 258048 u16
#define FEA_B(s) (550912u + (size_t)(s)*33554432u)  // 4 x 16777216 u16

// A-image u16 offsets within AH
#define A_S0   0
#define A_S(s) (36864 + ((s)-1)*73728)  // s = 1..3

// LDS sub-tile size (u16 elems): 3 rows x 130 cols x 36 stride
#define SUBT 14040

typedef __attribute__((ext_vector_type(4))) short  v4s;
typedef __attribute__((ext_vector_type(8))) short  v8s;
typedef __attribute__((ext_vector_type(4))) float  v4f;

__device__ __forceinline__ ushort f2bf(float f) {
    unsigned u = __builtin_bit_cast(unsigned, f);
    unsigned r = u + 0x7FFFu + ((u >> 16) & 1u);
    return (ushort)(r >> 16);
}

// ---------------------------------------------------------------------------
__global__ __launch_bounds__(64) void mask_kernel(
    const float* __restrict__ gum, const float* __restrict__ par,
    float* __restrict__ chm, float* __restrict__ out_tail)
{
    int c = threadIdx.x;
    #pragma unroll
    for (int i = 0; i < 4; ++i) {
        int base = (c*4 + i)*2;
        float g0 = -logf(-logf(gum[base]));
        float g1 = -logf(-logf(gum[base+1]));
        float a0 = par[base] + g0, a1 = par[base+1] + g1;
        float mx = fmaxf(a0, a1);
        float e0 = expf(a0 - mx), e1 = expf(a1 - mx);
        float inv = 1.0f / (e0 + e1);
        float m0 = e0*inv, m1 = e1*inv;
        chm[base] = m0; chm[base+1] = m1;
        out_tail[base] = m0; out_tail[base+1] = m1;
    }
}

// ---------------------------------------------------------------------------
// Build bf16 A-images (gate-folded weights) + bf16 pw weights.
__global__ __launch_bounds__(256) void prep_kernel(
    const float* __restrict__ w0, const float* __restrict__ w1,
    const float* __restrict__ w2, const float* __restrict__ w3,
    const float* __restrict__ wc, const float* __restrict__ chm,
    ushort* __restrict__ AH, ushort* __restrict__ pwA)
{
    int idx = blockIdx.x*256 + threadIdx.x;   // < 274432
    if (idx < 36864) {
        int blk = idx >> 11;            // c*9+t, 0..17
        int r3  = idx & 2047;
        int oc = r3 >> 5, icl = r3 & 31;
        int cc = blk / 9, t = blk - 9*cc;
        int ic = cc*32 + icl;
        AH[idx] = f2bf(w0[(oc*64 + ic)*9 + t]);
    } else if (idx < 258048) {
        int j = idx - 36864;
        int s = 1 + j / 73728;
        int r = j % 73728;
        int blk = r >> 12;              // 0..17
        int r3  = r & 4095;
        int ocM = r3 >> 5, icl = r3 & 31;
        int cc = blk / 9, t = blk - 9*cc;
        int ic = cc*32 + icl;
        int oc = ocM >> 1, set = ocM & 1;
        const float* wsrc = (s == 1) ? w1 : (s == 2 ? w2 : w3);
        AH[idx] = f2bf(wsrc[(oc*64 + ic)*9 + t] * chm[(ic*4 + s)*2 + set]);
    } else {
        int r = idx - 258048;           // < 16384
        pwA[r] = f2bf(wc[r]);
    }
}

// ---------------------------------------------------------------------------
// MFMA conv, pure bf16. Block = one (b,h) row, 128 px. M = 64*NSETS rows.
// Round-7: SINGLE-PHASE schedule. Rounds 5/6 proved the 128-reg budget at
// 4 waves/SIMD spills catastrophically -> occupancy lever dead. Back to the
// verified round-4 geometry (256 thr, 2M x 2N, MT = MOC/32,
// launch_bounds(256,2) = 256-reg budget), but BOTH 32-ic chunks get their
// own LDS sub-tile (2 x 14040 u16 = 56 KB, 2 blocks/CU = 112 < 160 KB):
//   issue(0); issue(1); prolog; zero-halos; scatter(0); scatter(1);
//   ONE barrier; computeAll (18 taps, ring-4 bridging the chunk boundary).
// Removes both mid-kernel vmcnt-draining barriers; all 12 staging loads
// overlap in one burst; one long MFMA+ds_read run.
// LDS layout per sub-tile: sB[colIdx*36 + (ic ^ (((colIdx>>3)&7)<<2))] —
// 3-bit XOR swizzle (4-way write conflict); reads = two aligned b64 loads
// reassembled in jj order. Halo zero: ONLY cols {ry*130+0, ry*130+129} of
// each sub-tile, disjoint from scatter (cols 1..128). All algebra identical
// to the round-4 PASSED kernel.
template<int NSETS, bool INF32>
__global__ __launch_bounds__(256, 2) void conv_bf16(
    const void* __restrict__ inv, const ushort* __restrict__ A,
    const float* __restrict__ chm, const float* __restrict__ spa,
    ushort* __restrict__ feaOut, int stage)
{
    constexpr int MOC = 64*NSETS;
    constexpr int MT  = MOC/32;     // m-tiles per wave
    __shared__ __align__(16) ushort sB[2*SUBT]; // 56160 B

    const int tid  = threadIdx.x;
    const int lane = tid & 63, wave = tid >> 6;
    const int wrow = wave >> 1, wcol = wave & 1;
    const int q = lane >> 4, ln16 = lane & 15;
    // XCD-aware remap (grid 2048 = 8*256): contiguous (b,h) chunk per XCD.
    const int wk = (blockIdx.x & 7)*256 + (blockIdx.x >> 3);
    const int h = wk & 127, b = wk >> 7;

    v4f acc[MT][4];
    #pragma unroll
    for (int m = 0; m < MT; ++m)
        #pragma unroll
        for (int n = 0; n < 4; ++n) acc[m][n] = (v4f){0.f, 0.f, 0.f, 0.f};

    int aRow[MT];
    #pragma unroll
    for (int m = 0; m < MT; ++m)
        aRow[m] = (wrow*(MOC/2) + m*16 + ln16)*32 + q*8;

    // staging registers (both chunks live until scatter) + A-frag ring
    v8s stg[12];
    v4f stgF[24];
    v8s af[4][MT];

    auto issue = [&](int c) {
        const int ic0 = c*32;
        #pragma unroll
        for (int it = 0; it < 6; ++it) {
            int i  = it*256 + tid;     // [0,1536)
            int ry = i >> 9;           // 0..2
            int r  = i & 511;
            int ic = r >> 4, wv = r & 15;
            int gh = h - 1 + ry;
            if constexpr (INF32) {
                v4f a0 = (v4f){0.f,0.f,0.f,0.f}, a1 = a0;
                if ((unsigned)gh < 128u) {
                    const float* s = (const float*)inv +
                        ((size_t)((b*C_ + ic0 + ic)*H_ + gh)*W_ + wv*8);
                    a0 = *(const v4f*)(const void*)s;
                    a1 = *(const v4f*)(const void*)(s + 4);
                }
                stgF[(c*6+it)*2] = a0; stgF[(c*6+it)*2+1] = a1;
            } else {
                v8s v = (v8s){0,0,0,0,0,0,0,0};
                if ((unsigned)gh < 128u)
                    v = *(const v8s*)(const void*)((const ushort*)inv +
                        ((size_t)((b*C_ + ic0 + ic)*H_ + gh)*W_ + wv*8));
                stg[c*6+it] = v;
            }
        }
    };
    auto scatter = [&](int c) {
        ushort* sBc = sB + c*SUBT;
        #pragma unroll
        for (int it = 0; it < 6; ++it) {
            int i  = it*256 + tid;
            int ry = i >> 9;
            int r  = i & 511;
            int ic = r >> 4, wv = r & 15;
            int colBase = ry*130 + wv*8 + 1;
            ushort vals[8];
            if constexpr (INF32) {
                #pragma unroll
                for (int j = 0; j < 4; ++j) {
                    vals[j]   = f2bf(stgF[(c*6+it)*2][j]);
                    vals[4+j] = f2bf(stgF[(c*6+it)*2+1][j]);
                }
            } else {
                #pragma unroll
                for (int j = 0; j < 8; ++j) vals[j] = (ushort)stg[c*6+it][j];
            }
            #pragma unroll
            for (int j = 0; j < 8; ++j) {
                int colIdx = colBase + j;
                int s3 = (colIdx >> 3) & 7;
                sBc[colIdx*36 + (ic ^ (s3 << 2))] = vals[j];
            }
        }
    };
    auto prolog = [&]() {
        #pragma unroll
        for (int tp = 0; tp < 3; ++tp)
            #pragma unroll
            for (int m = 0; m < MT; ++m)
                af[tp][m] = *(const v8s*)(const void*)(A + tp*MOC*32 + aRow[m]);
    };
    // 18 uninterrupted tap-steps; A-chunks are contiguous (tap tt at
    // A + tt*MOC*32), ring-4 prefetch bridges the chunk boundary.
    auto computeAll = [&]() {
        #pragma unroll
        for (int tt = 0; tt < 18; ++tt) {
            if (tt < 15) {
                #pragma unroll
                for (int m = 0; m < MT; ++m)
                    af[(tt+3)&3][m] = *(const v8s*)(const void*)(A + (tt+3)*MOC*32 + aRow[m]);
            }
            const int c  = tt/9, t = tt - 9*c;
            const int ky = t/3, kx = t - 3*(t/3);
            const ushort* sBc = sB + c*SUBT;
            #pragma unroll
            for (int nt = 0; nt < 4; ++nt) {
                int colIdx = ky*130 + wcol*64 + nt*16 + ln16 + kx;
                int s3 = (colIdx >> 3) & 7;
                int base = colIdx*36 + ((q ^ (s3 >> 1)) << 3);
                int lo = base + ((s3 & 1) << 2);
                int hi = base + (((s3 & 1) ^ 1) << 2);
                v4s va = *(const v4s*)(const void*)(sBc + lo);   // ic jj 0..3
                v4s vb = *(const v4s*)(const void*)(sBc + hi);   // ic jj 4..7
                v8s bf = __builtin_shufflevector(va, vb, 0, 1, 2, 3, 4, 5, 6, 7);
                #pragma unroll
                for (int m = 0; m < MT; ++m)
                    acc[m][nt] = __builtin_amdgcn_mfma_f32_16x16x32_bf16(af[tt&3][m], bf, acc[m][nt], 0, 0, 0);
            }
        }
    };

    // -------- single-phase schedule --------
    issue(0);                 // chunk-0 fea loads in flight
    issue(1);                 // chunk-1 fea loads in flight (12 total)
    prolog();                 // A taps 0-2 in flight
    // zero ONLY halo columns of both sub-tiles (disjoint from scatter).
    if (tid < 216) {
        int colSel = tid / 36;          // 0..5
        int icz    = tid - colSel*36;   // 0..35
        int ry     = colSel >> 1;
        int colIdx = ry*130 + ((colSel & 1) ? 129 : 0);
        sB[colIdx*36 + icz] = 0;
        sB[SUBT + colIdx*36 + icz] = 0;
    }
    scatter(0);               // waits chunk-0 loads; chunk-1 stays in flight
    scatter(1);
    __syncthreads();          // the ONLY barrier: both tiles + halos ready
    computeAll();

    // epilogue: gates + relu, bf16 store (round-4 verified algebra)
    const float* spaRow = &spa[b*HW_ + h*W_];
    #pragma unroll
    for (int nt = 0; nt < 4; ++nt) {
        int px = wcol*64 + nt*16 + ln16;
        float sp = spaRow[px];
        #pragma unroll
        for (int m = 0; m < MT; ++m) {
            if constexpr (NSETS == 2) {
                #pragma unroll
                for (int rp = 0; rp < 2; ++rp) {
                    int oc = wrow*32 + m*8 + q*2 + rp;
                    float md = chm[(oc*4 + stage)*2 + 0];
                    float ms = chm[(oc*4 + stage)*2 + 1];
                    float f = acc[m][nt][2*rp]*(ms*sp + md)
                            + acc[m][nt][2*rp+1]*((ms + md)*sp);
                    feaOut[((size_t)(b*C_ + oc)*H_ + h)*W_ + px] = f2bf(fmaxf(f, 0.f));
                }
            } else {
                #pragma unroll
                for (int r = 0; r < 4; ++r) {
                    int oc = wrow*32 + m*16 + q*4 + r;
                    float md = chm[(oc*4 + stage)*2 + 0];
                    float ms = chm[(oc*4 + stage)*2 + 1];
                    float f = acc[m][nt][r]*(ms*sp + md);
                    feaOut[((size_t)(b*C_ + oc)*H_ + h)*W_ + px] = f2bf(fmaxf(f, 0.f));
                }
            }
        }
    }
}

// ---------------------------------------------------------------------------
// Final pointwise: out[b,o,px] = sum_{k=0..255} wc[o][k]*fea_{k/64}[k%64][px] + bc[o]
// Block = 64 px of one (b,h) row. MFMA: M=64, N=64, K=256.
// (exact round-4 verified version)
__global__ __launch_bounds__(256, 2) void pw_final(
    const ushort* __restrict__ fea, const ushort* __restrict__ pwA,
    const float* __restrict__ bc, float* __restrict__ out)
{
    __shared__ __align__(16) ushort sF[64*260];   // 33280 B

    const int tid  = threadIdx.x;
    const int lane = tid & 63, wave = tid >> 6;
    const int wrow = wave >> 1, wcol = wave & 1;
    const int q = lane >> 4, ln16 = lane & 15;
    const int half = blockIdx.x & 1;
    const int h = (blockIdx.x >> 1) & 127;
    const int b = blockIdx.x >> 8;
    const int px0 = half*64;

    {
        v8s stg[8];
        #pragma unroll
        for (int it = 0; it < 8; ++it) {
            int i  = it*256 + tid;   // [0,2048)
            int s  = i >> 9;
            int r  = i & 511;
            int ic = r >> 3, pxv = r & 7;
            stg[it] = *(const v8s*)(const void*)(
                fea + (size_t)s*OUT_ELEMS + ((size_t)(b*C_ + ic)*H_ + h)*W_ + px0 + pxv*8);
        }
        #pragma unroll
        for (int it = 0; it < 8; ++it) {
            int i  = it*256 + tid;
            int s  = i >> 9;
            int r  = i & 511;
            int ic = r >> 3, pxv = r & 7;
            int kS = (s*64 + ic) ^ ((pxv & 3) << 3);
            ushort* dst = &sF[(pxv*8)*260 + kS];
            #pragma unroll
            for (int j = 0; j < 8; ++j) dst[j*260] = (ushort)stg[it][j];
        }
    }
    __syncthreads();

    v4f acc[2][2];
    #pragma unroll
    for (int m = 0; m < 2; ++m)
        #pragma unroll
        for (int n = 0; n < 2; ++n) acc[m][n] = (v4f){0.f, 0.f, 0.f, 0.f};

    #pragma unroll
    for (int ks = 0; ks < 8; ++ks) {
        v8s a[2];
        #pragma unroll
        for (int m = 0; m < 2; ++m)
            a[m] = *(const v8s*)(const void*)(pwA + (wrow*32 + m*16 + ln16)*256 + ks*32 + q*8);
        #pragma unroll
        for (int n = 0; n < 2; ++n) {
            int px = wcol*32 + n*16 + ln16;
            int swz = (px >> 3) & 3;
            v4s va = *(const v4s*)(const void*)(sF + px*260 + ks*32 + ((q ^ swz) << 3));
            v4s vb = *(const v4s*)(const void*)(sF + px*260 + ks*32 + ((q ^ swz) << 3) + 4);
            v8s bf = __builtin_shufflevector(va, vb, 0, 1, 2, 3, 4, 5, 6, 7);
            #pragma unroll
            for (int m = 0; m < 2; ++m)
                acc[m][n] = __builtin_amdgcn_mfma_f32_16x16x32_bf16(a[m], bf, acc[m][n], 0, 0, 0);
        }
    }

    #pragma unroll
    for (int n = 0; n < 2; ++n) {
        int px = px0 + wcol*32 + n*16 + ln16;
        #pragma unroll
        for (int m = 0; m < 2; ++m)
            #pragma unroll
            for (int r = 0; r < 4; ++r) {
                int o = wrow*32 + m*16 + q*4 + r;
                out[((size_t)(b*C_ + o)*H_ + h)*W_ + px] = acc[m][n][r] + bc[o];
            }
    }
}

// ---------------------------------------------------------------------------
extern "C" void kernel_launch(void* const* d_in, const int* in_sizes, int n_in,
                              void* d_out, int out_size, void* d_ws, size_t ws_size,
                              hipStream_t stream)
{
    const float* x0  = (const float*)d_in[0];
    const float* spa = (const float*)d_in[1];
    const float* gum = (const float*)d_in[2];
    const float* par = (const float*)d_in[3];
    const float* w0  = (const float*)d_in[4];
    const float* w1  = (const float*)d_in[5];
    const float* w2  = (const float*)d_in[6];
    const float* w3  = (const float*)d_in[7];
    const float* wc  = (const float*)d_in[8];
    const float* bc  = (const float*)d_in[9];
    float* out = (float*)d_out;
    char*  ws  = (char*)d_ws;

    float*  chm = (float*)(ws + CHM_B);
    ushort* pwA = (ushort*)(ws + PWA_B);
    ushort* AH  = (ushort*)(ws + AH_B);
    ushort* fea0 = (ushort*)(ws + FEA_B(0));
    ushort* fea1 = (ushort*)(ws + FEA_B(1));
    ushort* fea2 = (ushort*)(ws + FEA_B(2));
    ushort* fea3 = (ushort*)(ws + FEA_B(3));

    mask_kernel<<<1, 64, 0, stream>>>(gum, par, chm, out + OUT_ELEMS);
    prep_kernel<<<1072, 256, 0, stream>>>(w0, w1, w2, w3, wc, chm, AH, pwA);

    conv_bf16<1, true ><<<2048, 256, 0, stream>>>(x0,   AH + A_S0,  chm, spa, fea0, 0);
    conv_bf16<2, false><<<2048, 256, 0, stream>>>(fea0, AH + A_S(1), chm, spa, fea1, 1);
    conv_bf16<2, false><<<2048, 256, 0, stream>>>(fea1, AH + A_S(2), chm, spa, fea2, 2);
    conv_bf16<2, false><<<2048, 256, 0, stream>>>(fea2, AH + A_S(3), chm, spa, fea3, 3);

    pw_final<<<4096, 256, 0, stream>>>(fea0, pwA, bc, out);
}